// Round 9
// baseline (801.228 us; speedup 1.0000x reference)
//
#include <hip/hip_runtime.h>
#include <math.h>

// PraxisNano: B=4, T=8192, H=512, E=2048, C=64, stride=32
// Inputs: float32. Output: float32. Internal: bf16 MFMA, __sinf.
// r9 = r8's verified GEMM pair + fused elementwise chain:
//   tri_ln: LN1-stats + TriLinear + residual + LN2 in ONE kernel (512 thr =
//   full H row per chunk; x read once into registers; block-reduce stats).
//   gather_slice absorbs save_carry (ping-pong carry buffers, no race).
// GEMM1 (N=2048): gemm_w 256x256 counted-vmcnt pipeline (r7/r8).
// GEMM2 (N=512): gemm_db 128x128 256-thr drain-dbuf (r4/r8).
// T2 both-sides XOR swizzle (PMC: conflicts==0) + T1 XCD swizzle in both.
#define TB 4
#define TT 8192
#define TH 512
#define TE 2048
#define NCHUNK 256
#define GCTOT 1024          // TB*NCHUNK

typedef unsigned short u16;
typedef short bf8v __attribute__((ext_vector_type(8)));   // 8 bf16 MFMA frag
typedef float f4v __attribute__((ext_vector_type(4)));    // MFMA accumulator

__device__ __forceinline__ float bu2f(u16 u) {
    unsigned int x = ((unsigned int)u) << 16; float f; __builtin_memcpy(&f, &x, 4); return f;
}
__device__ __forceinline__ u16 f2bu(float f) {
    unsigned int x; __builtin_memcpy(&x, &f, 4);
    x = x + 0x7fffu + ((x >> 16) & 1u);   // RNE
    return (u16)(x >> 16);
}

// ---------------- composite TriLinear matrix, transposed: Mt[s][t] = ((W2.tri)(W1.tri))[t][s]
__global__ __launch_bounds__(256) void make_Mt(const float* __restrict__ W1,
                                               const float* __restrict__ W2,
                                               float* __restrict__ Mt) {
    __shared__ float w1[64 * 64];
    __shared__ float w2[64 * 64];
    for (int i = threadIdx.x; i < 4096; i += 256) { w1[i] = W1[i]; w2[i] = W2[i]; }
    __syncthreads();
    for (int i = threadIdx.x; i < 4096; i += 256) {
        int t = i >> 6, s = i & 63;
        float a = 0.f;
        if (t >= s) for (int k = s; k <= t; ++k) a += w2[t * 64 + k] * w1[k * 64 + s];
        Mt[s * 64 + t] = a;
    }
}

// ---------------- transpose f32 (R x C) -> bf16 (C x R)
__global__ __launch_bounds__(256) void transpose_b(const float* __restrict__ in,
                                                   u16* __restrict__ out, int R, int C) {
    __shared__ u16 tile[64][65];
    const int bx = blockIdx.x, by = blockIdx.y;
    const int tx = threadIdx.x & 63, ty = threadIdx.x >> 6;
#pragma unroll
    for (int i = 0; i < 16; ++i) {
        int r = ty + i * 4;
        tile[r][tx] = f2bu(in[(size_t)(by * 64 + r) * C + bx * 64 + tx]);
    }
    __syncthreads();
#pragma unroll
    for (int i = 0; i < 16; ++i) {
        int r = ty + i * 4;
        out[(size_t)(bx * 64 + r) * R + by * 64 + tx] = tile[tx][r];
    }
}

// ---------------- fused LN1-stats + TriLinear + residual + LN2 for one slice.
// One block (512 thr) per chunk: thread = one h column over the chunk's 64 rows.
// x read ONCE into registers; LN1/LN2 stats via wave-shfl + LDS block reduce.
__global__ __launch_bounds__(512) void tri_ln(const float* __restrict__ x,
                                              const float* __restrict__ g1v,
                                              const float* __restrict__ b1v,
                                              const float* __restrict__ Mt,
                                              const float* __restrict__ g2v,
                                              const float* __restrict__ b2v,
                                              u16* __restrict__ c2s,
                                              u16* __restrict__ h2s,
                                              int gc0) {
    __shared__ float red[64][8][2];    // per-row wave partials (sum, sumsq)
    __shared__ float2 ms[64];          // per-row (mean, rstd)
    const int ln = blockIdx.x;
    const int gc = gc0 + ln;
    const int b = gc >> 8, n = gc & 255;
    const int h = threadIdx.x;                   // 0..511
    const int wave = h >> 6, lane = h & 63;
    const int base = n * 32;

    // ---- load the 64 x-rows for this chunk (clamped), once
    float xv[64];
#pragma unroll
    for (int s = 0; s < 64; ++s) {
        int pos = base + s; if (pos > TT - 1) pos = TT - 1;
        xv[s] = x[((size_t)b * TT + pos) * TH + h];
    }
    // ---- LN1 stats per row s (over H=512)
#pragma unroll
    for (int s = 0; s < 64; ++s) {
        float s1 = xv[s], s2 = xv[s] * xv[s];
#pragma unroll
        for (int o = 32; o; o >>= 1) { s1 += __shfl_xor(s1, o); s2 += __shfl_xor(s2, o); }
        if (lane == 0) { red[s][wave][0] = s1; red[s][wave][1] = s2; }
    }
    __syncthreads();
    if (h < 64) {
        float s1 = 0.f, s2 = 0.f;
#pragma unroll
        for (int w = 0; w < 8; ++w) { s1 += red[h][w][0]; s2 += red[h][w][1]; }
        const float mean = s1 * (1.f / TH);
        float var = s2 * (1.f / TH) - mean * mean;
        if (var < 0.f) var = 0.f;
        ms[h] = make_float2(mean, rsqrtf(var + 1e-5f));
    }
    __syncthreads();

    // ---- TriLinear: acc[t] = sum_s Mt[s][t] * cn(s)
    const float gh = g1v[h], bh = b1v[h];
    float acc[64];
#pragma unroll
    for (int t = 0; t < 64; ++t) acc[t] = 0.f;
    for (int s = 0; s < 64; ++s) {
        const float cn = (xv[s] - ms[s].x) * ms[s].y * gh + bh;
        const float* m = Mt + s * 64;
#pragma unroll
        for (int t = 0; t < 64; ++t) acc[t] += m[t] * cn;
    }
    __syncthreads();                             // all ms/red reads done; safe to reuse

    // ---- c2 = acc + resid; write c2s; LN2 partials
#pragma unroll
    for (int t = 0; t < 64; ++t) {
        acc[t] += xv[t];
        c2s[(size_t)(ln * 64 + t) * TH + h] = f2bu(acc[t]);
        float s1 = acc[t], s2 = acc[t] * acc[t];
#pragma unroll
        for (int o = 32; o; o >>= 1) { s1 += __shfl_xor(s1, o); s2 += __shfl_xor(s2, o); }
        if (lane == 0) { red[t][wave][0] = s1; red[t][wave][1] = s2; }
    }
    __syncthreads();
    if (h < 64) {
        float s1 = 0.f, s2 = 0.f;
#pragma unroll
        for (int w = 0; w < 8; ++w) { s1 += red[h][w][0]; s2 += red[h][w][1]; }
        const float mean = s1 * (1.f / TH);
        float var = s2 * (1.f / TH) - mean * mean;
        if (var < 0.f) var = 0.f;
        ms[h] = make_float2(mean, rsqrtf(var + 1e-5f));
    }
    __syncthreads();
    // ---- LN2 apply -> h2s
    const float g2h = g2v[h], b2h = b2v[h];
#pragma unroll
    for (int t = 0; t < 64; ++t)
        h2s[(size_t)(ln * 64 + t) * TH + h] = f2bu((acc[t] - ms[t].x) * ms[t].y * g2h + b2h);
}

// ---------------- GEMM1: 256x256, per-wave 128x64, counted-vmcnt dbuf (r7/r8)
// MODE 1: C = __sinf(acc + bias);  MODE 2: C = acc + bias + addp
template <int MODE>
__global__ __launch_bounds__(512, 2) void gemm_w(const u16* __restrict__ A,    // M x K bf16
                                                 const u16* __restrict__ Bt,   // N x K bf16
                                                 u16* __restrict__ C,          // M x N bf16
                                                 const float* __restrict__ bias,
                                                 const u16* __restrict__ addp,
                                                 int N, int K) {
    __shared__ __attribute__((aligned(16))) u16 lA[2][256 * 64];   // 64 KiB
    __shared__ __attribute__((aligned(16))) u16 lB[2][256 * 64];   // 64 KiB
    const int tid = threadIdx.x;
    const int wave = tid >> 6;             // 0..7
    const int lane = tid & 63;
    const int wr = wave >> 2;              // 0..1 (M): rows wr*128..+128
    const int wc = wave & 3;               // 0..3 (N): cols wc*64..+64
    const int fr = lane & 15;
    const int fq = (lane >> 4) << 3;       // 0,8,16,24 (u16)
    const int s8 = (fr & 7) << 3;          // swizzle XOR (u16)

    // T1: XCD-chunked block swizzle (bijective when nwg%8==0)
    int bx = blockIdx.x, by = blockIdx.y;
    const int gx = gridDim.x;
    const int nwg = gx * (int)gridDim.y;
    if ((nwg & 7) == 0) {
        const int bid = by * gx + bx;
        const int swz = (bid & 7) * (nwg >> 3) + (bid >> 3);
        bx = swz % gx; by = swz / gx;
    }
    const int bm = by << 8;
    const int bn = bx << 8;

    // staging addresses: row srow (+i*64), source chunk XOR'ed by row&7
    const int srow = tid >> 3;                          // 0..63
    const int gch = ((tid & 7) ^ (srow & 7)) << 3;      // u16 offset
    const u16* pa = A + (size_t)(bm + srow) * K + gch;
    const u16* pb = Bt + (size_t)(bn + srow) * K + gch;
    const int ldsw = wave << 9;                         // wave-uniform base (u16)

    const int NT = K >> 6;
    f4v acc[8][4] = {};

    auto stage = [&](int t, int buf) {
        const size_t ko = (size_t)t << 6;
#pragma unroll
        for (int i = 0; i < 4; ++i)
            __builtin_amdgcn_global_load_lds(
                (const __attribute__((address_space(1))) void*)(pa + (size_t)(i * 64) * K + ko),
                (__attribute__((address_space(3))) void*)(&lA[buf][(i << 12) + ldsw]), 16, 0, 0);
#pragma unroll
        for (int i = 0; i < 4; ++i)
            __builtin_amdgcn_global_load_lds(
                (const __attribute__((address_space(1))) void*)(pb + (size_t)(i * 64) * K + ko),
                (__attribute__((address_space(3))) void*)(&lB[buf][(i << 12) + ldsw]), 16, 0, 0);
    };

    // prologue: tiles 0,1 in flight (16 loads); counted wait confirms tile 0.
    stage(0, 0);
    stage(1, 1);
    asm volatile("s_waitcnt vmcnt(8)" ::: "memory");
    asm volatile("s_barrier" ::: "memory");

    const int arow0 = (wr << 7) + fr;      // + mi*16
    const int brow0 = (wc << 6) + fr;      // + ni*16
    const int c0 = fq ^ s8;                // slice ks=0 swizzled col (u16)
    const int c1 = (32 + fq) ^ s8;         // slice ks=32 (XOR on chunk bits)

    for (int t = 0; t < NT; ++t) {
        const int buf = t & 1;
        const u16* la = lA[buf];
        const u16* lb = lB[buf];
        // ---- read ALL fragments of this tile (24 x ds_read_b128)
        bf8v af[8][2], bf[4][2];
#pragma unroll
        for (int mi = 0; mi < 8; ++mi) {
            af[mi][0] = *(const bf8v*)(la + ((arow0 + (mi << 4)) << 6) + c0);
            af[mi][1] = *(const bf8v*)(la + ((arow0 + (mi << 4)) << 6) + c1);
        }
#pragma unroll
        for (int ni = 0; ni < 4; ++ni) {
            bf[ni][0] = *(const bf8v*)(lb + ((brow0 + (ni << 4)) << 6) + c0);
            bf[ni][1] = *(const bf8v*)(lb + ((brow0 + (ni << 4)) << 6) + c1);
        }
        asm volatile("s_waitcnt lgkmcnt(0)" ::: "memory");
        __builtin_amdgcn_sched_barrier(0);
        asm volatile("s_barrier" ::: "memory");          // all waves done reading buf
        if (t + 2 < NT) stage(t + 2, buf);               // overwrite freed buffer, async
        // ---- 64 MFMA
        __builtin_amdgcn_s_setprio(1);
#pragma unroll
        for (int ks = 0; ks < 2; ++ks)
#pragma unroll
            for (int mi = 0; mi < 8; ++mi)
#pragma unroll
                for (int ni = 0; ni < 4; ++ni)
                    acc[mi][ni] = __builtin_amdgcn_mfma_f32_16x16x32_bf16(af[mi][ks], bf[ni][ks], acc[mi][ni], 0, 0, 0);
        __builtin_amdgcn_s_setprio(0);
        // ---- confirm tile t+1 (counted), publish
        if (t + 1 < NT) {
            if (t + 2 < NT) asm volatile("s_waitcnt vmcnt(8)" ::: "memory");
            else            asm volatile("s_waitcnt vmcnt(0)" ::: "memory");
            asm volatile("s_barrier" ::: "memory");
        }
    }

    // ---- epilogue: C/D layout col=lane&15, row=(lane>>4)*4+r (m89/m91)
    const int rq = (lane >> 4) << 2;
#pragma unroll
    for (int mi = 0; mi < 8; ++mi) {
#pragma unroll
        for (int ni = 0; ni < 4; ++ni) {
            const int col = bn + (wc << 6) + (ni << 4) + fr;
            const float bv = bias[col];
#pragma unroll
            for (int r = 0; r < 4; ++r) {
                const int row = bm + (wr << 7) + (mi << 4) + rq + r;
                float v = acc[mi][ni][r] + bv;
                if (MODE == 1) v = __sinf(v);
                else v += bu2f(addp[(size_t)row * N + col]);
                C[(size_t)row * N + col] = f2bu(v);
            }
        }
    }
}

// ---------------- GEMM2: 128x128, 256 thr, drain-dbuf (r4/r8, verified)
// MODE 1: C = __sinf(acc + bias);  MODE 2: C = acc + bias + addp
template <int MODE>
__global__ __launch_bounds__(256) void gemm_db(const u16* __restrict__ A,    // M x K bf16
                                               const u16* __restrict__ Bt,   // N x K bf16
                                               u16* __restrict__ C,          // M x N bf16
                                               const float* __restrict__ bias,
                                               const u16* __restrict__ addp,
                                               int N, int K) {
    __shared__ __attribute__((aligned(16))) u16 lA[2][128 * 64];
    __shared__ __attribute__((aligned(16))) u16 lB[2][128 * 64];
    const int tid = threadIdx.x;
    const int wave = tid >> 6;
    const int lane = tid & 63;
    const int wr = wave >> 1;
    const int wc = wave & 1;
    const int fr = lane & 15;
    const int fq = (lane >> 4) << 3;       // 0,8,16,24 (u16)
    const int s8 = (fr & 7) << 3;          // swizzle XOR (u16)

    // T1: XCD-chunked block swizzle
    int bx = blockIdx.x, by = blockIdx.y;
    const int gx = gridDim.x;
    const int nwg = gx * (int)gridDim.y;
    if ((nwg & 7) == 0) {
        const int bid = by * gx + bx;
        const int swz = (bid & 7) * (nwg >> 3) + (bid >> 3);
        bx = swz % gx; by = swz / gx;
    }
    const int bm = by << 7;
    const int bn = bx << 7;

    // staging addresses: row srow (+i*32), source chunk XOR'ed by row&7
    const int srow = tid >> 3;                          // 0..31
    const int gch = ((tid & 7) ^ (srow & 7)) << 3;      // u16 offset
    const u16* pa = A + (size_t)(bm + srow) * K + gch;
    const u16* pb = Bt + (size_t)(bn + srow) * K + gch;
    const int ldsw = wave << 9;                         // wave base within a 32-row group (u16)

    const int NT = K >> 6;
    f4v acc[4][4] = {};

    auto stage = [&](int t, int buf) {
        const int ko = t << 6;
#pragma unroll
        for (int i = 0; i < 4; ++i) {
            __builtin_amdgcn_global_load_lds(
                (const __attribute__((address_space(1))) void*)(pa + (size_t)(i * 32) * K + ko),
                (__attribute__((address_space(3))) void*)(&lA[buf][(i << 11) + ldsw]), 16, 0, 0);
            __builtin_amdgcn_global_load_lds(
                (const __attribute__((address_space(1))) void*)(pb + (size_t)(i * 32) * K + ko),
                (__attribute__((address_space(3))) void*)(&lB[buf][(i << 11) + ldsw]), 16, 0, 0);
        }
    };

    stage(0, 0);
    __syncthreads();

    const int arow0 = (wr << 6) + fr;      // + mi*16
    const int brow0 = (wc << 6) + fr;      // + ni*16
    const int c0 = fq ^ s8;                // slice ks=0 swizzled col (u16)
    const int c1 = (32 + fq) ^ s8;         // slice ks=32 (XOR on chunk bits)

    int buf = 0;
    for (int t = 0; t < NT; ++t) {
        if (t + 1 < NT) stage(t + 1, buf ^ 1);   // prefetch overlaps this tile's compute
        const u16* la = lA[buf];
        const u16* lb = lB[buf];
#pragma unroll
        for (int half = 0; half < 2; ++half) {
            const int cc = half ? c1 : c0;
            bf8v af[4], bfv[4];
#pragma unroll
            for (int mi = 0; mi < 4; ++mi)
                af[mi] = *(const bf8v*)(la + ((arow0 + (mi << 4)) << 6) + cc);
#pragma unroll
            for (int ni = 0; ni < 4; ++ni)
                bfv[ni] = *(const bf8v*)(lb + ((brow0 + (ni << 4)) << 6) + cc);
#pragma unroll
            for (int mi = 0; mi < 4; ++mi)
#pragma unroll
                for (int ni = 0; ni < 4; ++ni)
                    acc[mi][ni] = __builtin_amdgcn_mfma_f32_16x16x32_bf16(af[mi], bfv[ni], acc[mi][ni], 0, 0, 0);
        }
        __syncthreads();                         // drains prefetch + frees buf for overwrite
        buf ^= 1;
    }

    // ---- epilogue: C/D layout col=lane&15, row=(lane>>4)*4+r (m89/m91)
    const int rq = (lane >> 4) << 2;
#pragma unroll
    for (int mi = 0; mi < 4; ++mi) {
#pragma unroll
        for (int ni = 0; ni < 4; ++ni) {
            const int col = bn + (wc << 6) + (ni << 4) + fr;
            const float bv = bias[col];
#pragma unroll
            for (int r = 0; r < 4; ++r) {
                const int row = bm + (wr << 6) + (mi << 4) + rq + r;
                float v = acc[mi][ni][r] + bv;
                if (MODE == 1) v = __sinf(v);
                else v += bu2f(addp[(size_t)row * N + col]);
                C[(size_t)row * N + col] = f2bu(v);
            }
        }
    }
}

// ---------------- per-slice gather -> FLOAT32 output + fused carry save.
// Blocks [0, SC*8): gather (reads cin for cross-slice boundary).
// Blocks [SC*8, SC*8+16): copy ocs's last chunk into cout (ping-pong, no race).
__global__ __launch_bounds__(256) void gather_slice(const u16* __restrict__ ocs,
                                                    const u16* __restrict__ cin,
                                                    u16* __restrict__ cout,
                                                    float* __restrict__ out,
                                                    int gc0, int SC) {
    if ((int)blockIdx.x >= (SC << 3)) {
        const int i = ((int)blockIdx.x - (SC << 3)) * 256 + threadIdx.x;   // 4096 uint4
        ((uint4*)cout)[i] = ((const uint4*)(ocs + (size_t)(SC - 1) * 64 * TH))[i];
        return;
    }
    const int idx = blockIdx.x * 256 + threadIdx.x;   // vec8 id within slice
    const int h8 = idx & 63;                          // TH/8
    const int prow = idx >> 6;                        // 0 .. SC*32-1
    const int ap = gc0 * 32 + prow;                   // linear (b,t) position index
    const int b = ap >> 13, t = ap & 8191;
    const int n = t >> 5, c = t & 31;
    const int ln = (b << 8) + n - gc0;                // covering chunk, slice-local
    uint4 r1 = *((const uint4*)ocs + (size_t)(ln * 64 + c) * 64 + h8);
    const u16* e1 = (const u16*)&r1;
    float ov[8];
    if (t < 32) {
#pragma unroll
        for (int i = 0; i < 8; ++i) ov[i] = bu2f(e1[i]);
    } else {
        uint4 r0;
        if (ln == 0) r0 = *((const uint4*)cin + (size_t)(c + 32) * 64 + h8);
        else         r0 = *((const uint4*)ocs + (size_t)((ln - 1) * 64 + c + 32) * 64 + h8);
        const u16* e0 = (const u16*)&r0;
#pragma unroll
        for (int i = 0; i < 8; ++i) ov[i] = 0.5f * (bu2f(e1[i]) + bu2f(e0[i]));
    }
    float4* dst = (float4*)(out + (size_t)ap * TH + h8 * 8);
    dst[0] = make_float4(ov[0], ov[1], ov[2], ov[3]);
    dst[1] = make_float4(ov[4], ov[5], ov[6], ov[7]);
}

extern "C" void kernel_launch(void* const* d_in, const int* in_sizes, int n_in,
                              void* d_out, int out_size, void* d_ws, size_t ws_size,
                              hipStream_t stream) {
    const float* x   = (const float*)d_in[0];
    const float* g1  = (const float*)d_in[1];
    const float* b1  = (const float*)d_in[2];
    const float* W1  = (const float*)d_in[3];
    const float* W2  = (const float*)d_in[4];
    const float* g2  = (const float*)d_in[5];
    const float* b2  = (const float*)d_in[6];
    const float* fw1 = (const float*)d_in[7];
    const float* fb1 = (const float*)d_in[8];
    const float* fw2 = (const float*)d_in[9];
    const float* fb2 = (const float*)d_in[10];
    float* out = (float*)d_out;
    char* ws = (char*)d_ws;

    size_t o = 0;
    auto take = [&](size_t n) { size_t r = o; o = (o + n + 255) & ~(size_t)255; return r; };
    float*  Mt    = (float*) (ws + take(64 * 64 * 4));
    u16*    f1t   = (u16*)   (ws + take((size_t)TE * TH * 2));
    u16*    f2t   = (u16*)   (ws + take((size_t)TH * TE * 2));
    u16*    carry = (u16*)   (ws + take((size_t)2 * 64 * TH * 2));   // ping-pong
    const size_t fixed = o;

    // Adaptive slice size (global chunks per slice). Min 4 so SR is a multiple
    // of 256 (gemm_w uses 256-row tiles); cap 256 so us stays L3-resident.
    int SC = 4;
    for (int cand = 256; cand >= 4; cand >>= 1) {
        size_t per = (size_t)cand * 64 * (TH * 2 * 3 + TE * 2) + 4 * 256;
        if (fixed + per <= ws_size) { SC = cand; break; }
    }
    u16* c2s = (u16*)(ws + take((size_t)SC * 64 * TH * 2));
    u16* h2s = (u16*)(ws + take((size_t)SC * 64 * TH * 2));
    u16* ocs = (u16*)(ws + take((size_t)SC * 64 * TH * 2));
    u16* us  = (u16*)(ws + take((size_t)SC * 64 * TE * 2));
    const int SR = SC * 64;

    make_Mt<<<1, 256, 0, stream>>>(W1, W2, Mt);
    transpose_b<<<dim3(TE / 64, TH / 64), 256, 0, stream>>>(fw1, f1t, TH, TE);
    transpose_b<<<dim3(TH / 64, TE / 64), 256, 0, stream>>>(fw2, f2t, TE, TH);

    int si = 0;
    for (int gc0 = 0; gc0 < GCTOT; gc0 += SC, ++si) {
        tri_ln<<<SC, 512, 0, stream>>>(x, g1, b1, Mt, g2, b2, c2s, h2s, gc0);
        gemm_w<1><<<dim3(TE / 256, SR / 256), 512, 0, stream>>>(
            h2s, f1t, us, fb1, (const u16*)nullptr, TE, TH);
        gemm_db<2><<<dim3(TH / 128, SR / 128), 256, 0, stream>>>(
            us, f2t, ocs, fb2, c2s, TH, TE);
        u16* cin  = carry + (size_t)(si & 1) * 64 * TH;
        u16* cout = carry + (size_t)((si + 1) & 1) * 64 * TH;
        gather_slice<<<SC * 8 + 16, 256, 0, stream>>>(ocs, cin, cout, out, gc0, SC);
    }
}

// Round 10
// 762.736 us; speedup vs baseline: 1.0505x; 1.0505x over previous
//
#include <hip/hip_runtime.h>
#include <math.h>

// PraxisNano: B=4, T=8192, H=512, E=2048, C=64, stride=32
// Inputs: float32. Output: float32. Internal: bf16 MFMA, __sinf.
// r10 = r8's verified GEMM pair + spill-free fusion:
//   ln_stats (global, once; r8-proven) -> tri2 (trilinear acc[64]-only +
//   residual via L2 re-read of x + fused LN2; NO xv[64] array -> no spill).
//   gather_slice absorbs save_carry (ping-pong carry buffers; r9-verified).
// GEMM1 (N=2048): gemm_w 256x256 counted-vmcnt pipeline (r7/r8) — measured at
//   its LDS-read-BW ceiling (25.7% MfmaUtil ~= 27% structural cap), untouched.
// GEMM2 (N=512): gemm_db 128x128 256-thr drain-dbuf (r4/r8), untouched.
#define TB 4
#define TT 8192
#define TH 512
#define TE 2048
#define NCHUNK 256
#define GCTOT 1024          // TB*NCHUNK

typedef unsigned short u16;
typedef short bf8v __attribute__((ext_vector_type(8)));   // 8 bf16 MFMA frag
typedef float f4v __attribute__((ext_vector_type(4)));    // MFMA accumulator

__device__ __forceinline__ float bu2f(u16 u) {
    unsigned int x = ((unsigned int)u) << 16; float f; __builtin_memcpy(&f, &x, 4); return f;
}
__device__ __forceinline__ u16 f2bu(float f) {
    unsigned int x; __builtin_memcpy(&x, &f, 4);
    x = x + 0x7fffu + ((x >> 16) & 1u);   // RNE
    return (u16)(x >> 16);
}

// ---------------- composite TriLinear matrix, transposed: Mt[s][t] = ((W2.tri)(W1.tri))[t][s]
__global__ __launch_bounds__(256) void make_Mt(const float* __restrict__ W1,
                                               const float* __restrict__ W2,
                                               float* __restrict__ Mt) {
    __shared__ float w1[64 * 64];
    __shared__ float w2[64 * 64];
    for (int i = threadIdx.x; i < 4096; i += 256) { w1[i] = W1[i]; w2[i] = W2[i]; }
    __syncthreads();
    for (int i = threadIdx.x; i < 4096; i += 256) {
        int t = i >> 6, s = i & 63;
        float a = 0.f;
        if (t >= s) for (int k = s; k <= t; ++k) a += w2[t * 64 + k] * w1[k * 64 + s];
        Mt[s * 64 + t] = a;
    }
}

// ---------------- transpose f32 (R x C) -> bf16 (C x R)
__global__ __launch_bounds__(256) void transpose_b(const float* __restrict__ in,
                                                   u16* __restrict__ out, int R, int C) {
    __shared__ u16 tile[64][65];
    const int bx = blockIdx.x, by = blockIdx.y;
    const int tx = threadIdx.x & 63, ty = threadIdx.x >> 6;
#pragma unroll
    for (int i = 0; i < 16; ++i) {
        int r = ty + i * 4;
        tile[r][tx] = f2bu(in[(size_t)(by * 64 + r) * C + bx * 64 + tx]);
    }
    __syncthreads();
#pragma unroll
    for (int i = 0; i < 16; ++i) {
        int r = ty + i * 4;
        out[(size_t)(bx * 64 + r) * R + by * 64 + tx] = tile[tx][r];
    }
}

// ---------------- LN1 stats per x-row (mean, rstd)  [r8-proven]
__global__ __launch_bounds__(256) void ln_stats(const float* __restrict__ x,
                                                float2* __restrict__ st) {
    const int wave = threadIdx.x >> 6, lane = threadIdx.x & 63;
    const size_t row = (size_t)blockIdx.x * 4 + wave;
    const float4* p = (const float4*)(x + row * TH);
    float4 a = p[lane * 2], b = p[lane * 2 + 1];
    float s = 0.f, q = 0.f;
    float v[8] = {a.x, a.y, a.z, a.w, b.x, b.y, b.z, b.w};
#pragma unroll
    for (int i = 0; i < 8; ++i) { s += v[i]; q += v[i] * v[i]; }
#pragma unroll
    for (int o = 32; o; o >>= 1) { s += __shfl_xor(s, o); q += __shfl_xor(q, o); }
    const float mean = s * (1.f / TH);
    float var = q * (1.f / TH) - mean * mean;
    if (var < 0.f) var = 0.f;
    if (lane == 0) st[row] = make_float2(mean, rsqrtf(var + 1e-5f));
}

// ---------------- fused TriLinear + residual + LN2 (spill-free).
// One block (512 thr) per chunk; thread = one h column. LN1 stats precomputed
// (st). acc[64] is the only big array (~88 VGPR total). Residual re-reads x
// (chunk = 128 KB, L2-hot from the s-loop). LN2 stats: wave shfl + LDS reduce.
__global__ __launch_bounds__(512) void tri2(const float* __restrict__ x,
                                            const float2* __restrict__ st,
                                            const float* __restrict__ g1v,
                                            const float* __restrict__ b1v,
                                            const float* __restrict__ Mt,
                                            const float* __restrict__ g2v,
                                            const float* __restrict__ b2v,
                                            u16* __restrict__ c2s,
                                            u16* __restrict__ h2s,
                                            int gc0) {
    __shared__ float red[64][8][2];    // per-row wave partials (sum, sumsq)
    __shared__ float2 ms[64];          // per-row (mean, rstd) for LN2
    const int ln = blockIdx.x;
    const int gc = gc0 + ln;
    const int b = gc >> 8, n = gc & 255;
    const int h = threadIdx.x;                   // 0..511
    const int wave = h >> 6, lane = h & 63;
    const int base = n * 32;
    const float gh = g1v[h], bh = b1v[h];

    float acc[64];
#pragma unroll
    for (int t = 0; t < 64; ++t) acc[t] = 0.f;
    for (int s = 0; s < 64; ++s) {
        int pos = base + s; if (pos > TT - 1) pos = TT - 1;
        const size_t ro = (size_t)b * TT + pos;
        const float2 mr = st[ro];
        const float cn = (x[ro * TH + h] - mr.x) * mr.y * gh + bh;
        const float* m = Mt + s * 64;
#pragma unroll
        for (int t = 0; t < 64; ++t) acc[t] += m[t] * cn;
    }

    // ---- c2 = acc + resid (x re-read, L2-hot); write c2s; LN2 partials
#pragma unroll
    for (int t = 0; t < 64; ++t) {
        int pos = base + t; if (pos > TT - 1) pos = TT - 1;
        const float resid = x[((size_t)b * TT + pos) * TH + h];
        acc[t] += resid;
        c2s[(size_t)(ln * 64 + t) * TH + h] = f2bu(acc[t]);
        float s1 = acc[t], s2 = acc[t] * acc[t];
#pragma unroll
        for (int o = 32; o; o >>= 1) { s1 += __shfl_xor(s1, o); s2 += __shfl_xor(s2, o); }
        if (lane == 0) { red[t][wave][0] = s1; red[t][wave][1] = s2; }
    }
    __syncthreads();
    if (h < 64) {
        float s1 = 0.f, s2 = 0.f;
#pragma unroll
        for (int w = 0; w < 8; ++w) { s1 += red[h][w][0]; s2 += red[h][w][1]; }
        const float mean = s1 * (1.f / TH);
        float var = s2 * (1.f / TH) - mean * mean;
        if (var < 0.f) var = 0.f;
        ms[h] = make_float2(mean, rsqrtf(var + 1e-5f));
    }
    __syncthreads();
    // ---- LN2 apply -> h2s
    const float g2h = g2v[h], b2h = b2v[h];
#pragma unroll
    for (int t = 0; t < 64; ++t)
        h2s[(size_t)(ln * 64 + t) * TH + h] = f2bu((acc[t] - ms[t].x) * ms[t].y * g2h + b2h);
}

// ---------------- GEMM1: 256x256, per-wave 128x64, counted-vmcnt dbuf (r7/r8)
// MODE 1: C = __sinf(acc + bias);  MODE 2: C = acc + bias + addp
template <int MODE>
__global__ __launch_bounds__(512, 2) void gemm_w(const u16* __restrict__ A,    // M x K bf16
                                                 const u16* __restrict__ Bt,   // N x K bf16
                                                 u16* __restrict__ C,          // M x N bf16
                                                 const float* __restrict__ bias,
                                                 const u16* __restrict__ addp,
                                                 int N, int K) {
    __shared__ __attribute__((aligned(16))) u16 lA[2][256 * 64];   // 64 KiB
    __shared__ __attribute__((aligned(16))) u16 lB[2][256 * 64];   // 64 KiB
    const int tid = threadIdx.x;
    const int wave = tid >> 6;             // 0..7
    const int lane = tid & 63;
    const int wr = wave >> 2;              // 0..1 (M): rows wr*128..+128
    const int wc = wave & 3;               // 0..3 (N): cols wc*64..+64
    const int fr = lane & 15;
    const int fq = (lane >> 4) << 3;       // 0,8,16,24 (u16)
    const int s8 = (fr & 7) << 3;          // swizzle XOR (u16)

    // T1: XCD-chunked block swizzle (bijective when nwg%8==0)
    int bx = blockIdx.x, by = blockIdx.y;
    const int gx = gridDim.x;
    const int nwg = gx * (int)gridDim.y;
    if ((nwg & 7) == 0) {
        const int bid = by * gx + bx;
        const int swz = (bid & 7) * (nwg >> 3) + (bid >> 3);
        bx = swz % gx; by = swz / gx;
    }
    const int bm = by << 8;
    const int bn = bx << 8;

    // staging addresses: row srow (+i*64), source chunk XOR'ed by row&7
    const int srow = tid >> 3;                          // 0..63
    const int gch = ((tid & 7) ^ (srow & 7)) << 3;      // u16 offset
    const u16* pa = A + (size_t)(bm + srow) * K + gch;
    const u16* pb = Bt + (size_t)(bn + srow) * K + gch;
    const int ldsw = wave << 9;                         // wave-uniform base (u16)

    const int NT = K >> 6;
    f4v acc[8][4] = {};

    auto stage = [&](int t, int buf) {
        const size_t ko = (size_t)t << 6;
#pragma unroll
        for (int i = 0; i < 4; ++i)
            __builtin_amdgcn_global_load_lds(
                (const __attribute__((address_space(1))) void*)(pa + (size_t)(i * 64) * K + ko),
                (__attribute__((address_space(3))) void*)(&lA[buf][(i << 12) + ldsw]), 16, 0, 0);
#pragma unroll
        for (int i = 0; i < 4; ++i)
            __builtin_amdgcn_global_load_lds(
                (const __attribute__((address_space(1))) void*)(pb + (size_t)(i * 64) * K + ko),
                (__attribute__((address_space(3))) void*)(&lB[buf][(i << 12) + ldsw]), 16, 0, 0);
    };

    // prologue: tiles 0,1 in flight (16 loads); counted wait confirms tile 0.
    stage(0, 0);
    stage(1, 1);
    asm volatile("s_waitcnt vmcnt(8)" ::: "memory");
    asm volatile("s_barrier" ::: "memory");

    const int arow0 = (wr << 7) + fr;      // + mi*16
    const int brow0 = (wc << 6) + fr;      // + ni*16
    const int c0 = fq ^ s8;                // slice ks=0 swizzled col (u16)
    const int c1 = (32 + fq) ^ s8;         // slice ks=32 (XOR on chunk bits)

    for (int t = 0; t < NT; ++t) {
        const int buf = t & 1;
        const u16* la = lA[buf];
        const u16* lb = lB[buf];
        // ---- read ALL fragments of this tile (24 x ds_read_b128)
        bf8v af[8][2], bf[4][2];
#pragma unroll
        for (int mi = 0; mi < 8; ++mi) {
            af[mi][0] = *(const bf8v*)(la + ((arow0 + (mi << 4)) << 6) + c0);
            af[mi][1] = *(const bf8v*)(la + ((arow0 + (mi << 4)) << 6) + c1);
        }
#pragma unroll
        for (int ni = 0; ni < 4; ++ni) {
            bf[ni][0] = *(const bf8v*)(lb + ((brow0 + (ni << 4)) << 6) + c0);
            bf[ni][1] = *(const bf8v*)(lb + ((brow0 + (ni << 4)) << 6) + c1);
        }
        asm volatile("s_waitcnt lgkmcnt(0)" ::: "memory");
        __builtin_amdgcn_sched_barrier(0);
        asm volatile("s_barrier" ::: "memory");          // all waves done reading buf
        if (t + 2 < NT) stage(t + 2, buf);               // overwrite freed buffer, async
        // ---- 64 MFMA
        __builtin_amdgcn_s_setprio(1);
#pragma unroll
        for (int ks = 0; ks < 2; ++ks)
#pragma unroll
            for (int mi = 0; mi < 8; ++mi)
#pragma unroll
                for (int ni = 0; ni < 4; ++ni)
                    acc[mi][ni] = __builtin_amdgcn_mfma_f32_16x16x32_bf16(af[mi][ks], bf[ni][ks], acc[mi][ni], 0, 0, 0);
        __builtin_amdgcn_s_setprio(0);
        // ---- confirm tile t+1 (counted), publish
        if (t + 1 < NT) {
            if (t + 2 < NT) asm volatile("s_waitcnt vmcnt(8)" ::: "memory");
            else            asm volatile("s_waitcnt vmcnt(0)" ::: "memory");
            asm volatile("s_barrier" ::: "memory");
        }
    }

    // ---- epilogue: C/D layout col=lane&15, row=(lane>>4)*4+r (m89/m91)
    const int rq = (lane >> 4) << 2;
#pragma unroll
    for (int mi = 0; mi < 8; ++mi) {
#pragma unroll
        for (int ni = 0; ni < 4; ++ni) {
            const int col = bn + (wc << 6) + (ni << 4) + fr;
            const float bv = bias[col];
#pragma unroll
            for (int r = 0; r < 4; ++r) {
                const int row = bm + (wr << 7) + (mi << 4) + rq + r;
                float v = acc[mi][ni][r] + bv;
                if (MODE == 1) v = __sinf(v);
                else v += bu2f(addp[(size_t)row * N + col]);
                C[(size_t)row * N + col] = f2bu(v);
            }
        }
    }
}

// ---------------- GEMM2: 128x128, 256 thr, drain-dbuf (r4/r8, verified)
// MODE 1: C = __sinf(acc + bias);  MODE 2: C = acc + bias + addp
template <int MODE>
__global__ __launch_bounds__(256) void gemm_db(const u16* __restrict__ A,    // M x K bf16
                                               const u16* __restrict__ Bt,   // N x K bf16
                                               u16* __restrict__ C,          // M x N bf16
                                               const float* __restrict__ bias,
                                               const u16* __restrict__ addp,
                                               int N, int K) {
    __shared__ __attribute__((aligned(16))) u16 lA[2][128 * 64];
    __shared__ __attribute__((aligned(16))) u16 lB[2][128 * 64];
    const int tid = threadIdx.x;
    const int wave = tid >> 6;
    const int lane = tid & 63;
    const int wr = wave >> 1;
    const int wc = wave & 1;
    const int fr = lane & 15;
    const int fq = (lane >> 4) << 3;       // 0,8,16,24 (u16)
    const int s8 = (fr & 7) << 3;          // swizzle XOR (u16)

    // T1: XCD-chunked block swizzle
    int bx = blockIdx.x, by = blockIdx.y;
    const int gx = gridDim.x;
    const int nwg = gx * (int)gridDim.y;
    if ((nwg & 7) == 0) {
        const int bid = by * gx + bx;
        const int swz = (bid & 7) * (nwg >> 3) + (bid >> 3);
        bx = swz % gx; by = swz / gx;
    }
    const int bm = by << 7;
    const int bn = bx << 7;

    // staging addresses: row srow (+i*32), source chunk XOR'ed by row&7
    const int srow = tid >> 3;                          // 0..31
    const int gch = ((tid & 7) ^ (srow & 7)) << 3;      // u16 offset
    const u16* pa = A + (size_t)(bm + srow) * K + gch;
    const u16* pb = Bt + (size_t)(bn + srow) * K + gch;
    const int ldsw = wave << 9;                         // wave base within a 32-row group (u16)

    const int NT = K >> 6;
    f4v acc[4][4] = {};

    auto stage = [&](int t, int buf) {
        const int ko = t << 6;
#pragma unroll
        for (int i = 0; i < 4; ++i) {
            __builtin_amdgcn_global_load_lds(
                (const __attribute__((address_space(1))) void*)(pa + (size_t)(i * 32) * K + ko),
                (__attribute__((address_space(3))) void*)(&lA[buf][(i << 11) + ldsw]), 16, 0, 0);
            __builtin_amdgcn_global_load_lds(
                (const __attribute__((address_space(1))) void*)(pb + (size_t)(i * 32) * K + ko),
                (__attribute__((address_space(3))) void*)(&lB[buf][(i << 11) + ldsw]), 16, 0, 0);
        }
    };

    stage(0, 0);
    __syncthreads();

    const int arow0 = (wr << 6) + fr;      // + mi*16
    const int brow0 = (wc << 6) + fr;      // + ni*16
    const int c0 = fq ^ s8;                // slice ks=0 swizzled col (u16)
    const int c1 = (32 + fq) ^ s8;         // slice ks=32 (XOR on chunk bits)

    int buf = 0;
    for (int t = 0; t < NT; ++t) {
        if (t + 1 < NT) stage(t + 1, buf ^ 1);   // prefetch overlaps this tile's compute
        const u16* la = lA[buf];
        const u16* lb = lB[buf];
#pragma unroll
        for (int half = 0; half < 2; ++half) {
            const int cc = half ? c1 : c0;
            bf8v af[4], bfv[4];
#pragma unroll
            for (int mi = 0; mi < 4; ++mi)
                af[mi] = *(const bf8v*)(la + ((arow0 + (mi << 4)) << 6) + cc);
#pragma unroll
            for (int ni = 0; ni < 4; ++ni)
                bfv[ni] = *(const bf8v*)(lb + ((brow0 + (ni << 4)) << 6) + cc);
#pragma unroll
            for (int mi = 0; mi < 4; ++mi)
#pragma unroll
                for (int ni = 0; ni < 4; ++ni)
                    acc[mi][ni] = __builtin_amdgcn_mfma_f32_16x16x32_bf16(af[mi], bfv[ni], acc[mi][ni], 0, 0, 0);
        }
        __syncthreads();                         // drains prefetch + frees buf for overwrite
        buf ^= 1;
    }

    // ---- epilogue: C/D layout col=lane&15, row=(lane>>4)*4+r (m89/m91)
    const int rq = (lane >> 4) << 2;
#pragma unroll
    for (int mi = 0; mi < 4; ++mi) {
#pragma unroll
        for (int ni = 0; ni < 4; ++ni) {
            const int col = bn + (wc << 6) + (ni << 4) + fr;
            const float bv = bias[col];
#pragma unroll
            for (int r = 0; r < 4; ++r) {
                const int row = bm + (wr << 6) + (mi << 4) + rq + r;
                float v = acc[mi][ni][r] + bv;
                if (MODE == 1) v = __sinf(v);
                else v += bu2f(addp[(size_t)row * N + col]);
                C[(size_t)row * N + col] = f2bu(v);
            }
        }
    }
}

// ---------------- per-slice gather -> FLOAT32 output + fused carry save.
// Blocks [0, SC*8): gather (reads cin for cross-slice boundary).
// Blocks [SC*8, SC*8+16): copy ocs's last chunk into cout (ping-pong, no race).
__global__ __launch_bounds__(256) void gather_slice(const u16* __restrict__ ocs,
                                                    const u16* __restrict__ cin,
                                                    u16* __restrict__ cout,
                                                    float* __restrict__ out,
                                                    int gc0, int SC) {
    if ((int)blockIdx.x >= (SC << 3)) {
        const int i = ((int)blockIdx.x - (SC << 3)) * 256 + threadIdx.x;   // 4096 uint4
        ((uint4*)cout)[i] = ((const uint4*)(ocs + (size_t)(SC - 1) * 64 * TH))[i];
        return;
    }
    const int idx = blockIdx.x * 256 + threadIdx.x;   // vec8 id within slice
    const int h8 = idx & 63;                          // TH/8
    const int prow = idx >> 6;                        // 0 .. SC*32-1
    const int ap = gc0 * 32 + prow;                   // linear (b,t) position index
    const int b = ap >> 13, t = ap & 8191;
    const int n = t >> 5, c = t & 31;
    const int ln = (b << 8) + n - gc0;                // covering chunk, slice-local
    uint4 r1 = *((const uint4*)ocs + (size_t)(ln * 64 + c) * 64 + h8);
    const u16* e1 = (const u16*)&r1;
    float ov[8];
    if (t < 32) {
#pragma unroll
        for (int i = 0; i < 8; ++i) ov[i] = bu2f(e1[i]);
    } else {
        uint4 r0;
        if (ln == 0) r0 = *((const uint4*)cin + (size_t)(c + 32) * 64 + h8);
        else         r0 = *((const uint4*)ocs + (size_t)((ln - 1) * 64 + c + 32) * 64 + h8);
        const u16* e0 = (const u16*)&r0;
#pragma unroll
        for (int i = 0; i < 8; ++i) ov[i] = 0.5f * (bu2f(e1[i]) + bu2f(e0[i]));
    }
    float4* dst = (float4*)(out + (size_t)ap * TH + h8 * 8);
    dst[0] = make_float4(ov[0], ov[1], ov[2], ov[3]);
    dst[1] = make_float4(ov[4], ov[5], ov[6], ov[7]);
}

extern "C" void kernel_launch(void* const* d_in, const int* in_sizes, int n_in,
                              void* d_out, int out_size, void* d_ws, size_t ws_size,
                              hipStream_t stream) {
    const float* x   = (const float*)d_in[0];
    const float* g1  = (const float*)d_in[1];
    const float* b1  = (const float*)d_in[2];
    const float* W1  = (const float*)d_in[3];
    const float* W2  = (const float*)d_in[4];
    const float* g2  = (const float*)d_in[5];
    const float* b2  = (const float*)d_in[6];
    const float* fw1 = (const float*)d_in[7];
    const float* fb1 = (const float*)d_in[8];
    const float* fw2 = (const float*)d_in[9];
    const float* fb2 = (const float*)d_in[10];
    float* out = (float*)d_out;
    char* ws = (char*)d_ws;

    size_t o = 0;
    auto take = [&](size_t n) { size_t r = o; o = (o + n + 255) & ~(size_t)255; return r; };
    float*  Mt    = (float*) (ws + take(64 * 64 * 4));
    u16*    f1t   = (u16*)   (ws + take((size_t)TE * TH * 2));
    u16*    f2t   = (u16*)   (ws + take((size_t)TH * TE * 2));
    float2* st1   = (float2*)(ws + take((size_t)TB * TT * 8));
    u16*    carry = (u16*)   (ws + take((size_t)2 * 64 * TH * 2));   // ping-pong
    const size_t fixed = o;

    // Adaptive slice size (global chunks per slice). Min 4 so SR is a multiple
    // of 256 (gemm_w uses 256-row tiles); cap 256 so us stays L3-resident.
    int SC = 4;
    for (int cand = 256; cand >= 4; cand >>= 1) {
        size_t per = (size_t)cand * 64 * (TH * 2 * 3 + TE * 2) + 4 * 256;
        if (fixed + per <= ws_size) { SC = cand; break; }
    }
    u16* c2s = (u16*)(ws + take((size_t)SC * 64 * TH * 2));
    u16* h2s = (u16*)(ws + take((size_t)SC * 64 * TH * 2));
    u16* ocs = (u16*)(ws + take((size_t)SC * 64 * TH * 2));
    u16* us  = (u16*)(ws + take((size_t)SC * 64 * TE * 2));
    const int SR = SC * 64;

    make_Mt<<<1, 256, 0, stream>>>(W1, W2, Mt);
    transpose_b<<<dim3(TE / 64, TH / 64), 256, 0, stream>>>(fw1, f1t, TH, TE);
    transpose_b<<<dim3(TH / 64, TE / 64), 256, 0, stream>>>(fw2, f2t, TE, TH);
    ln_stats<<<(TB * TT) / 4, 256, 0, stream>>>(x, st1);

    int si = 0;
    for (int gc0 = 0; gc0 < GCTOT; gc0 += SC, ++si) {
        tri2<<<SC, 512, 0, stream>>>(x, st1, g1, b1, Mt, g2, b2, c2s, h2s, gc0);
        gemm_w<1><<<dim3(TE / 256, SR / 256), 512, 0, stream>>>(
            h2s, f1t, us, fb1, (const u16*)nullptr, TE, TH);
        gemm_db<2><<<dim3(TH / 128, SR / 128), 256, 0, stream>>>(
            us, f2t, ocs, fb2, c2s, TH, TE);
        u16* cin  = carry + (size_t)(si & 1) * 64 * TH;
        u16* cout = carry + (size_t)((si + 1) & 1) * 64 * TH;
        gather_slice<<<SC * 8 + 16, 256, 0, stream>>>(ocs, cin, cout, out, gc0, SC);
    }
}

// Round 11
// 680.333 us; speedup vs baseline: 1.1777x; 1.1211x over previous
//
#include <hip/hip_runtime.h>
#include <math.h>

// PraxisNano: B=4, T=8192, H=512, E=2048, C=64, stride=32
// Inputs: float32. Output: float32. Internal: bf16 MFMA, __sinf.
// r11 = r10 with tri2 split 4-way over t (grid-starvation fix):
//   tri2 was 1 block/CU (grid=SC=256) -> latency-bound at 13% HBM. Now
//   grid=(SC,4); block (ln,tb) computes t in [16*tb,16*tb+16): acc[16],
//   3-4 blocks/CU. Same accumulation order -> bit-identical outputs.
// GEMM1 (N=2048): gemm_w 256x256 counted-vmcnt pipeline (r7/r8), at its
//   LDS-read-BW structural ceiling (25.7% MfmaUtil), untouched.
// GEMM2 (N=512): gemm_db 128x128 256-thr drain-dbuf (r4/r8), untouched.
// gather_slice absorbs save_carry (ping-pong carry; r9/r10-verified).
#define TB 4
#define TT 8192
#define TH 512
#define TE 2048
#define NCHUNK 256
#define GCTOT 1024          // TB*NCHUNK

typedef unsigned short u16;
typedef short bf8v __attribute__((ext_vector_type(8)));   // 8 bf16 MFMA frag
typedef float f4v __attribute__((ext_vector_type(4)));    // MFMA accumulator

__device__ __forceinline__ float bu2f(u16 u) {
    unsigned int x = ((unsigned int)u) << 16; float f; __builtin_memcpy(&f, &x, 4); return f;
}
__device__ __forceinline__ u16 f2bu(float f) {
    unsigned int x; __builtin_memcpy(&x, &f, 4);
    x = x + 0x7fffu + ((x >> 16) & 1u);   // RNE
    return (u16)(x >> 16);
}

// ---------------- composite TriLinear matrix, transposed: Mt[s][t] = ((W2.tri)(W1.tri))[t][s]
__global__ __launch_bounds__(256) void make_Mt(const float* __restrict__ W1,
                                               const float* __restrict__ W2,
                                               float* __restrict__ Mt) {
    __shared__ float w1[64 * 64];
    __shared__ float w2[64 * 64];
    for (int i = threadIdx.x; i < 4096; i += 256) { w1[i] = W1[i]; w2[i] = W2[i]; }
    __syncthreads();
    for (int i = threadIdx.x; i < 4096; i += 256) {
        int t = i >> 6, s = i & 63;
        float a = 0.f;
        if (t >= s) for (int k = s; k <= t; ++k) a += w2[t * 64 + k] * w1[k * 64 + s];
        Mt[s * 64 + t] = a;
    }
}

// ---------------- transpose f32 (R x C) -> bf16 (C x R)
__global__ __launch_bounds__(256) void transpose_b(const float* __restrict__ in,
                                                   u16* __restrict__ out, int R, int C) {
    __shared__ u16 tile[64][65];
    const int bx = blockIdx.x, by = blockIdx.y;
    const int tx = threadIdx.x & 63, ty = threadIdx.x >> 6;
#pragma unroll
    for (int i = 0; i < 16; ++i) {
        int r = ty + i * 4;
        tile[r][tx] = f2bu(in[(size_t)(by * 64 + r) * C + bx * 64 + tx]);
    }
    __syncthreads();
#pragma unroll
    for (int i = 0; i < 16; ++i) {
        int r = ty + i * 4;
        out[(size_t)(bx * 64 + r) * R + by * 64 + tx] = tile[tx][r];
    }
}

// ---------------- LN1 stats per x-row (mean, rstd)  [r8-proven]
__global__ __launch_bounds__(256) void ln_stats(const float* __restrict__ x,
                                                float2* __restrict__ st) {
    const int wave = threadIdx.x >> 6, lane = threadIdx.x & 63;
    const size_t row = (size_t)blockIdx.x * 4 + wave;
    const float4* p = (const float4*)(x + row * TH);
    float4 a = p[lane * 2], b = p[lane * 2 + 1];
    float s = 0.f, q = 0.f;
    float v[8] = {a.x, a.y, a.z, a.w, b.x, b.y, b.z, b.w};
#pragma unroll
    for (int i = 0; i < 8; ++i) { s += v[i]; q += v[i] * v[i]; }
#pragma unroll
    for (int o = 32; o; o >>= 1) { s += __shfl_xor(s, o); q += __shfl_xor(q, o); }
    const float mean = s * (1.f / TH);
    float var = q * (1.f / TH) - mean * mean;
    if (var < 0.f) var = 0.f;
    if (lane == 0) st[row] = make_float2(mean, rsqrtf(var + 1e-5f));
}

// ---------------- fused TriLinear + residual + LN2, 4-way t-split.
// Block (ln, tb): chunk ln of slice, t rows [16*tb, 16*tb+16). 512 thr = one
// h column each. LN1 stats precomputed (st). acc[16] only (~40 VGPR).
// Concurrent tb-blocks re-read the same 64 s-rows -> L2/L3 shared.
__global__ __launch_bounds__(512) void tri2(const float* __restrict__ x,
                                            const float2* __restrict__ st,
                                            const float* __restrict__ g1v,
                                            const float* __restrict__ b1v,
                                            const float* __restrict__ Mt,
                                            const float* __restrict__ g2v,
                                            const float* __restrict__ b2v,
                                            u16* __restrict__ c2s,
                                            u16* __restrict__ h2s,
                                            int gc0) {
    __shared__ float red[16][8][2];    // per-row wave partials (sum, sumsq)
    __shared__ float2 ms[16];          // per-row (mean, rstd) for LN2
    const int ln = blockIdx.x;
    const int t0 = (int)blockIdx.y << 4;         // 0,16,32,48
    const int gc = gc0 + ln;
    const int b = gc >> 8, n = gc & 255;
    const int h = threadIdx.x;                   // 0..511
    const int wave = h >> 6, lane = h & 63;
    const int base = n * 32;
    const float gh = g1v[h], bh = b1v[h];

    float acc[16];
#pragma unroll
    for (int tt = 0; tt < 16; ++tt) acc[tt] = 0.f;
    for (int s = 0; s < 64; ++s) {
        int pos = base + s; if (pos > TT - 1) pos = TT - 1;
        const size_t ro = (size_t)b * TT + pos;
        const float2 mr = st[ro];
        const float cn = (x[ro * TH + h] - mr.x) * mr.y * gh + bh;
        const float* m = Mt + s * 64 + t0;
#pragma unroll
        for (int tt = 0; tt < 16; ++tt) acc[tt] += m[tt] * cn;
    }

    // ---- c2 = acc + resid (x re-read, cache-hot); write c2s; LN2 partials
#pragma unroll
    for (int tt = 0; tt < 16; ++tt) {
        const int t = t0 + tt;
        int pos = base + t; if (pos > TT - 1) pos = TT - 1;
        const float resid = x[((size_t)b * TT + pos) * TH + h];
        acc[tt] += resid;
        c2s[(size_t)(ln * 64 + t) * TH + h] = f2bu(acc[tt]);
        float s1 = acc[tt], s2 = acc[tt] * acc[tt];
#pragma unroll
        for (int o = 32; o; o >>= 1) { s1 += __shfl_xor(s1, o); s2 += __shfl_xor(s2, o); }
        if (lane == 0) { red[tt][wave][0] = s1; red[tt][wave][1] = s2; }
    }
    __syncthreads();
    if (h < 16) {
        float s1 = 0.f, s2 = 0.f;
#pragma unroll
        for (int w = 0; w < 8; ++w) { s1 += red[h][w][0]; s2 += red[h][w][1]; }
        const float mean = s1 * (1.f / TH);
        float var = s2 * (1.f / TH) - mean * mean;
        if (var < 0.f) var = 0.f;
        ms[h] = make_float2(mean, rsqrtf(var + 1e-5f));
    }
    __syncthreads();
    // ---- LN2 apply -> h2s
    const float g2h = g2v[h], b2h = b2v[h];
#pragma unroll
    for (int tt = 0; tt < 16; ++tt)
        h2s[(size_t)(ln * 64 + t0 + tt) * TH + h] = f2bu((acc[tt] - ms[tt].x) * ms[tt].y * g2h + b2h);
}

// ---------------- GEMM1: 256x256, per-wave 128x64, counted-vmcnt dbuf (r7/r8)
// MODE 1: C = __sinf(acc + bias);  MODE 2: C = acc + bias + addp
template <int MODE>
__global__ __launch_bounds__(512, 2) void gemm_w(const u16* __restrict__ A,    // M x K bf16
                                                 const u16* __restrict__ Bt,   // N x K bf16
                                                 u16* __restrict__ C,          // M x N bf16
                                                 const float* __restrict__ bias,
                                                 const u16* __restrict__ addp,
                                                 int N, int K) {
    __shared__ __attribute__((aligned(16))) u16 lA[2][256 * 64];   // 64 KiB
    __shared__ __attribute__((aligned(16))) u16 lB[2][256 * 64];   // 64 KiB
    const int tid = threadIdx.x;
    const int wave = tid >> 6;             // 0..7
    const int lane = tid & 63;
    const int wr = wave >> 2;              // 0..1 (M): rows wr*128..+128
    const int wc = wave & 3;               // 0..3 (N): cols wc*64..+64
    const int fr = lane & 15;
    const int fq = (lane >> 4) << 3;       // 0,8,16,24 (u16)
    const int s8 = (fr & 7) << 3;          // swizzle XOR (u16)

    // T1: XCD-chunked block swizzle (bijective when nwg%8==0)
    int bx = blockIdx.x, by = blockIdx.y;
    const int gx = gridDim.x;
    const int nwg = gx * (int)gridDim.y;
    if ((nwg & 7) == 0) {
        const int bid = by * gx + bx;
        const int swz = (bid & 7) * (nwg >> 3) + (bid >> 3);
        bx = swz % gx; by = swz / gx;
    }
    const int bm = by << 8;
    const int bn = bx << 8;

    // staging addresses: row srow (+i*64), source chunk XOR'ed by row&7
    const int srow = tid >> 3;                          // 0..63
    const int gch = ((tid & 7) ^ (srow & 7)) << 3;      // u16 offset
    const u16* pa = A + (size_t)(bm + srow) * K + gch;
    const u16* pb = Bt + (size_t)(bn + srow) * K + gch;
    const int ldsw = wave << 9;                         // wave-uniform base (u16)

    const int NT = K >> 6;
    f4v acc[8][4] = {};

    auto stage = [&](int t, int buf) {
        const size_t ko = (size_t)t << 6;
#pragma unroll
        for (int i = 0; i < 4; ++i)
            __builtin_amdgcn_global_load_lds(
                (const __attribute__((address_space(1))) void*)(pa + (size_t)(i * 64) * K + ko),
                (__attribute__((address_space(3))) void*)(&lA[buf][(i << 12) + ldsw]), 16, 0, 0);
#pragma unroll
        for (int i = 0; i < 4; ++i)
            __builtin_amdgcn_global_load_lds(
                (const __attribute__((address_space(1))) void*)(pb + (size_t)(i * 64) * K + ko),
                (__attribute__((address_space(3))) void*)(&lB[buf][(i << 12) + ldsw]), 16, 0, 0);
    };

    // prologue: tiles 0,1 in flight (16 loads); counted wait confirms tile 0.
    stage(0, 0);
    stage(1, 1);
    asm volatile("s_waitcnt vmcnt(8)" ::: "memory");
    asm volatile("s_barrier" ::: "memory");

    const int arow0 = (wr << 7) + fr;      // + mi*16
    const int brow0 = (wc << 6) + fr;      // + ni*16
    const int c0 = fq ^ s8;                // slice ks=0 swizzled col (u16)
    const int c1 = (32 + fq) ^ s8;         // slice ks=32 (XOR on chunk bits)

    for (int t = 0; t < NT; ++t) {
        const int buf = t & 1;
        const u16* la = lA[buf];
        const u16* lb = lB[buf];
        // ---- read ALL fragments of this tile (24 x ds_read_b128)
        bf8v af[8][2], bf[4][2];
#pragma unroll
        for (int mi = 0; mi < 8; ++mi) {
            af[mi][0] = *(const bf8v*)(la + ((arow0 + (mi << 4)) << 6) + c0);
            af[mi][1] = *(const bf8v*)(la + ((arow0 + (mi << 4)) << 6) + c1);
        }
#pragma unroll
        for (int ni = 0; ni < 4; ++ni) {
            bf[ni][0] = *(const bf8v*)(lb + ((brow0 + (ni << 4)) << 6) + c0);
            bf[ni][1] = *(const bf8v*)(lb + ((brow0 + (ni << 4)) << 6) + c1);
        }
        asm volatile("s_waitcnt lgkmcnt(0)" ::: "memory");
        __builtin_amdgcn_sched_barrier(0);
        asm volatile("s_barrier" ::: "memory");          // all waves done reading buf
        if (t + 2 < NT) stage(t + 2, buf);               // overwrite freed buffer, async
        // ---- 64 MFMA
        __builtin_amdgcn_s_setprio(1);
#pragma unroll
        for (int ks = 0; ks < 2; ++ks)
#pragma unroll
            for (int mi = 0; mi < 8; ++mi)
#pragma unroll
                for (int ni = 0; ni < 4; ++ni)
                    acc[mi][ni] = __builtin_amdgcn_mfma_f32_16x16x32_bf16(af[mi][ks], bf[ni][ks], acc[mi][ni], 0, 0, 0);
        __builtin_amdgcn_s_setprio(0);
        // ---- confirm tile t+1 (counted), publish
        if (t + 1 < NT) {
            if (t + 2 < NT) asm volatile("s_waitcnt vmcnt(8)" ::: "memory");
            else            asm volatile("s_waitcnt vmcnt(0)" ::: "memory");
            asm volatile("s_barrier" ::: "memory");
        }
    }

    // ---- epilogue: C/D layout col=lane&15, row=(lane>>4)*4+r (m89/m91)
    const int rq = (lane >> 4) << 2;
#pragma unroll
    for (int mi = 0; mi < 8; ++mi) {
#pragma unroll
        for (int ni = 0; ni < 4; ++ni) {
            const int col = bn + (wc << 6) + (ni << 4) + fr;
            const float bv = bias[col];
#pragma unroll
            for (int r = 0; r < 4; ++r) {
                const int row = bm + (wr << 7) + (mi << 4) + rq + r;
                float v = acc[mi][ni][r] + bv;
                if (MODE == 1) v = __sinf(v);
                else v += bu2f(addp[(size_t)row * N + col]);
                C[(size_t)row * N + col] = f2bu(v);
            }
        }
    }
}

// ---------------- GEMM2: 128x128, 256 thr, drain-dbuf (r4/r8, verified)
// MODE 1: C = __sinf(acc + bias);  MODE 2: C = acc + bias + addp
template <int MODE>
__global__ __launch_bounds__(256) void gemm_db(const u16* __restrict__ A,    // M x K bf16
                                               const u16* __restrict__ Bt,   // N x K bf16
                                               u16* __restrict__ C,          // M x N bf16
                                               const float* __restrict__ bias,
                                               const u16* __restrict__ addp,
                                               int N, int K) {
    __shared__ __attribute__((aligned(16))) u16 lA[2][128 * 64];
    __shared__ __attribute__((aligned(16))) u16 lB[2][128 * 64];
    const int tid = threadIdx.x;
    const int wave = tid >> 6;
    const int lane = tid & 63;
    const int wr = wave >> 1;
    const int wc = wave & 1;
    const int fr = lane & 15;
    const int fq = (lane >> 4) << 3;       // 0,8,16,24 (u16)
    const int s8 = (fr & 7) << 3;          // swizzle XOR (u16)

    // T1: XCD-chunked block swizzle
    int bx = blockIdx.x, by = blockIdx.y;
    const int gx = gridDim.x;
    const int nwg = gx * (int)gridDim.y;
    if ((nwg & 7) == 0) {
        const int bid = by * gx + bx;
        const int swz = (bid & 7) * (nwg >> 3) + (bid >> 3);
        bx = swz % gx; by = swz / gx;
    }
    const int bm = by << 7;
    const int bn = bx << 7;

    // staging addresses: row srow (+i*32), source chunk XOR'ed by row&7
    const int srow = tid >> 3;                          // 0..31
    const int gch = ((tid & 7) ^ (srow & 7)) << 3;      // u16 offset
    const u16* pa = A + (size_t)(bm + srow) * K + gch;
    const u16* pb = Bt + (size_t)(bn + srow) * K + gch;
    const int ldsw = wave << 9;                         // wave base within a 32-row group (u16)

    const int NT = K >> 6;
    f4v acc[4][4] = {};

    auto stage = [&](int t, int buf) {
        const int ko = t << 6;
#pragma unroll
        for (int i = 0; i < 4; ++i) {
            __builtin_amdgcn_global_load_lds(
                (const __attribute__((address_space(1))) void*)(pa + (size_t)(i * 32) * K + ko),
                (__attribute__((address_space(3))) void*)(&lA[buf][(i << 11) + ldsw]), 16, 0, 0);
            __builtin_amdgcn_global_load_lds(
                (const __attribute__((address_space(1))) void*)(pb + (size_t)(i * 32) * K + ko),
                (__attribute__((address_space(3))) void*)(&lB[buf][(i << 11) + ldsw]), 16, 0, 0);
        }
    };

    stage(0, 0);
    __syncthreads();

    const int arow0 = (wr << 6) + fr;      // + mi*16
    const int brow0 = (wc << 6) + fr;      // + ni*16
    const int c0 = fq ^ s8;                // slice ks=0 swizzled col (u16)
    const int c1 = (32 + fq) ^ s8;         // slice ks=32 (XOR on chunk bits)

    int buf = 0;
    for (int t = 0; t < NT; ++t) {
        if (t + 1 < NT) stage(t + 1, buf ^ 1);   // prefetch overlaps this tile's compute
        const u16* la = lA[buf];
        const u16* lb = lB[buf];
#pragma unroll
        for (int half = 0; half < 2; ++half) {
            const int cc = half ? c1 : c0;
            bf8v af[4], bfv[4];
#pragma unroll
            for (int mi = 0; mi < 4; ++mi)
                af[mi] = *(const bf8v*)(la + ((arow0 + (mi << 4)) << 6) + cc);
#pragma unroll
            for (int ni = 0; ni < 4; ++ni)
                bfv[ni] = *(const bf8v*)(lb + ((brow0 + (ni << 4)) << 6) + cc);
#pragma unroll
            for (int mi = 0; mi < 4; ++mi)
#pragma unroll
                for (int ni = 0; ni < 4; ++ni)
                    acc[mi][ni] = __builtin_amdgcn_mfma_f32_16x16x32_bf16(af[mi], bfv[ni], acc[mi][ni], 0, 0, 0);
        }
        __syncthreads();                         // drains prefetch + frees buf for overwrite
        buf ^= 1;
    }

    // ---- epilogue: C/D layout col=lane&15, row=(lane>>4)*4+r (m89/m91)
    const int rq = (lane >> 4) << 2;
#pragma unroll
    for (int mi = 0; mi < 4; ++mi) {
#pragma unroll
        for (int ni = 0; ni < 4; ++ni) {
            const int col = bn + (wc << 6) + (ni << 4) + fr;
            const float bv = bias[col];
#pragma unroll
            for (int r = 0; r < 4; ++r) {
                const int row = bm + (wr << 6) + (mi << 4) + rq + r;
                float v = acc[mi][ni][r] + bv;
                if (MODE == 1) v = __sinf(v);
                else v += bu2f(addp[(size_t)row * N + col]);
                C[(size_t)row * N + col] = f2bu(v);
            }
        }
    }
}

// ---------------- per-slice gather -> FLOAT32 output + fused carry save.
// Blocks [0, SC*8): gather (reads cin for cross-slice boundary).
// Blocks [SC*8, SC*8+16): copy ocs's last chunk into cout (ping-pong, no race).
__global__ __launch_bounds__(256) void gather_slice(const u16* __restrict__ ocs,
                                                    const u16* __restrict__ cin,
                                                    u16* __restrict__ cout,
                                                    float* __restrict__ out,
                                                    int gc0, int SC) {
    if ((int)blockIdx.x >= (SC << 3)) {
        const int i = ((int)blockIdx.x - (SC << 3)) * 256 + threadIdx.x;   // 4096 uint4
        ((uint4*)cout)[i] = ((const uint4*)(ocs + (size_t)(SC - 1) * 64 * TH))[i];
        return;
    }
    const int idx = blockIdx.x * 256 + threadIdx.x;   // vec8 id within slice
    const int h8 = idx & 63;                          // TH/8
    const int prow = idx >> 6;                        // 0 .. SC*32-1
    const int ap = gc0 * 32 + prow;                   // linear (b,t) position index
    const int b = ap >> 13, t = ap & 8191;
    const int n = t >> 5, c = t & 31;
    const int ln = (b << 8) + n - gc0;                // covering chunk, slice-local
    uint4 r1 = *((const uint4*)ocs + (size_t)(ln * 64 + c) * 64 + h8);
    const u16* e1 = (const u16*)&r1;
    float ov[8];
    if (t < 32) {
#pragma unroll
        for (int i = 0; i < 8; ++i) ov[i] = bu2f(e1[i]);
    } else {
        uint4 r0;
        if (ln == 0) r0 = *((const uint4*)cin + (size_t)(c + 32) * 64 + h8);
        else         r0 = *((const uint4*)ocs + (size_t)((ln - 1) * 64 + c + 32) * 64 + h8);
        const u16* e0 = (const u16*)&r0;
#pragma unroll
        for (int i = 0; i < 8; ++i) ov[i] = 0.5f * (bu2f(e1[i]) + bu2f(e0[i]));
    }
    float4* dst = (float4*)(out + (size_t)ap * TH + h8 * 8);
    dst[0] = make_float4(ov[0], ov[1], ov[2], ov[3]);
    dst[1] = make_float4(ov[4], ov[5], ov[6], ov[7]);
}

extern "C" void kernel_launch(void* const* d_in, const int* in_sizes, int n_in,
                              void* d_out, int out_size, void* d_ws, size_t ws_size,
                              hipStream_t stream) {
    const float* x   = (const float*)d_in[0];
    const float* g1  = (const float*)d_in[1];
    const float* b1  = (const float*)d_in[2];
    const float* W1  = (const float*)d_in[3];
    const float* W2  = (const float*)d_in[4];
    const float* g2  = (const float*)d_in[5];
    const float* b2  = (const float*)d_in[6];
    const float* fw1 = (const float*)d_in[7];
    const float* fb1 = (const float*)d_in[8];
    const float* fw2 = (const float*)d_in[9];
    const float* fb2 = (const float*)d_in[10];
    float* out = (float*)d_out;
    char* ws = (char*)d_ws;

    size_t o = 0;
    auto take = [&](size_t n) { size_t r = o; o = (o + n + 255) & ~(size_t)255; return r; };
    float*  Mt    = (float*) (ws + take(64 * 64 * 4));
    u16*    f1t   = (u16*)   (ws + take((size_t)TE * TH * 2));
    u16*    f2t   = (u16*)   (ws + take((size_t)TH * TE * 2));
    float2* st1   = (float2*)(ws + take((size_t)TB * TT * 8));
    u16*    carry = (u16*)   (ws + take((size_t)2 * 64 * TH * 2));   // ping-pong
    const size_t fixed = o;

    // Adaptive slice size (global chunks per slice). Min 4 so SR is a multiple
    // of 256 (gemm_w uses 256-row tiles); cap 256 so us stays L3-resident.
    int SC = 4;
    for (int cand = 256; cand >= 4; cand >>= 1) {
        size_t per = (size_t)cand * 64 * (TH * 2 * 3 + TE * 2) + 4 * 256;
        if (fixed + per <= ws_size) { SC = cand; break; }
    }
    u16* c2s = (u16*)(ws + take((size_t)SC * 64 * TH * 2));
    u16* h2s = (u16*)(ws + take((size_t)SC * 64 * TH * 2));
    u16* ocs = (u16*)(ws + take((size_t)SC * 64 * TH * 2));
    u16* us  = (u16*)(ws + take((size_t)SC * 64 * TE * 2));
    const int SR = SC * 64;

    make_Mt<<<1, 256, 0, stream>>>(W1, W2, Mt);
    transpose_b<<<dim3(TE / 64, TH / 64), 256, 0, stream>>>(fw1, f1t, TH, TE);
    transpose_b<<<dim3(TH / 64, TE / 64), 256, 0, stream>>>(fw2, f2t, TE, TH);
    ln_stats<<<(TB * TT) / 4, 256, 0, stream>>>(x, st1);

    int si = 0;
    for (int gc0 = 0; gc0 < GCTOT; gc0 += SC, ++si) {
        tri2<<<dim3(SC, 4), 512, 0, stream>>>(x, st1, g1, b1, Mt, g2, b2, c2s, h2s, gc0);
        gemm_w<1><<<dim3(TE / 256, SR / 256), 512, 0, stream>>>(
            h2s, f1t, us, fb1, (const u16*)nullptr, TE, TH);
        gemm_db<2><<<dim3(TH / 128, SR / 128), 256, 0, stream>>>(
            us, f2t, ocs, fb2, c2s, TH, TE);
        u16* cin  = carry + (size_t)(si & 1) * 64 * TH;
        u16* cout = carry + (size_t)((si + 1) & 1) * 64 * TH;
        gather_slice<<<SC * 8 + 16, 256, 0, stream>>>(ocs, cin, cout, out, gc0, SC);
    }
}